// Round 3
// baseline (69.103 us; speedup 1.0000x reference)
//
#include <hip/hip_runtime.h>

#define NB 256          // threads per block (4 waves)
#define APT 32          // atoms per thread (N = NB*APT = 8192)
#define NTYPE 11
#define CPAD 13         // padded per-thread counter row
#define NATOMS 8192

__global__ __launch_bounds__(NB)
void typed_coords_kernel(const float* __restrict__ coords,
                         const int*   __restrict__ types,
                         const int*   __restrict__ num_atoms,
                         float* __restrict__ out,       // B*3N floats
                         float* __restrict__ out_cnt,   // B*NTYPE floats
                         float* __restrict__ out_off)   // B*NTYPE floats
{
    const int b    = blockIdx.x;
    const int tid  = threadIdx.x;
    const int lane = tid & 63;
    const int wave = tid >> 6;

    __shared__ unsigned short lds_src16[NATOMS];     // 16 KB inverse perm
    __shared__ unsigned short lds_cnt[NB * CPAD];    // 6.7 KB counters
    __shared__ int lds_counts[NTYPE];
    __shared__ int lds_off[NTYPE];

    const int na     = num_atoms[b];
    const int base_i = tid * APT;

    // ---- load my 32 types into registers (skip fully-invalid tails) ----
    int ty[APT];
    const int* tptr = types + (size_t)b * NATOMS + base_i;
    if (base_i < na) {
        #pragma unroll
        for (int g = 0; g < APT / 4; ++g) {
            int4 v = *reinterpret_cast<const int4*>(tptr + g * 4);
            ty[g * 4 + 0] = v.x;
            ty[g * 4 + 1] = v.y;
            ty[g * 4 + 2] = v.z;
            ty[g * 4 + 3] = v.w;
        }
    }

    // ---- per-thread histogram in own LDS row ----
    #pragma unroll
    for (int t = 0; t < CPAD; ++t) lds_cnt[tid * CPAD + t] = 0;
    if (base_i < na) {
        #pragma unroll
        for (int k = 0; k < APT; ++k) {              // static indices only
            if (base_i + k < na) lds_cnt[tid * CPAD + ty[k]] += 1;
        }
    }
    __syncthreads();

    // ---- per-type exclusive scan across the 256 thread rows ----
    // wave w handles types w, w+4, w+8
    for (int tt = wave; tt < NTYPE; tt += NB / 64) {
        int run = 0;
        #pragma unroll
        for (int s = 0; s < NB / 64; ++s) {
            int idx = (s * 64 + lane) * CPAD + tt;
            int v = lds_cnt[idx];
            int x = v;
            #pragma unroll
            for (int d = 1; d < 64; d <<= 1) {
                int n = __shfl_up(x, d);
                if (lane >= d) x += n;
            }
            lds_cnt[idx] = (unsigned short)(x - v + run);  // exclusive prefix
            run += __shfl(x, 63);
        }
        lds_counts[tt] = run;
    }
    __syncthreads();

    // ---- type offsets (exclusive cumsum over 11 types) ----
    if (tid == 0) {
        int acc = 0;
        #pragma unroll
        for (int t = 0; t < NTYPE; ++t) { lds_off[t] = acc; acc += lds_counts[t]; }
    }
    __syncthreads();

    if (tid < NTYPE) {
        out_cnt[(size_t)b * NTYPE + tid] = (float)lds_counts[tid];
        out_off[(size_t)b * NTYPE + tid] = (float)lds_off[tid];
    }

    // ---- scatter ranks -> inverse permutation in LDS ----
    if (base_i < na) {
        #pragma unroll
        for (int k = 0; k < APT; ++k) {
            if (base_i + k < na) {
                int t   = ty[k];
                int idx = tid * CPAD + t;
                int r   = lds_cnt[idx];
                lds_cnt[idx] = (unsigned short)(r + 1);
                lds_src16[lds_off[t] + r] = (unsigned short)(base_i + k);
            }
        }
    }
    // sentinel-fill invalid tail [na, N)  (disjoint from scatter region)
    for (int j = na + tid; j < NATOMS; j += NB) lds_src16[j] = 0xFFFFu;
    __syncthreads();

    // ---- gather + fully-coalesced float4 writeout ----
    const float* cbase = coords + (size_t)b * 3 * NATOMS;
    float*       obase = out    + (size_t)b * 3 * NATOMS;
    #pragma unroll
    for (int q = 0; q < NATOMS / (NB * 4); ++q) {    // 8 iterations, 4 slots/thread
        int j0 = (q * NB + tid) * 4;
        uint2 sp = *reinterpret_cast<const uint2*>(&lds_src16[j0]);
        int ss[4] = { (int)(sp.x & 0xFFFFu), (int)(sp.x >> 16),
                      (int)(sp.y & 0xFFFFu), (int)(sp.y >> 16) };
        float v[12];
        #pragma unroll
        for (int u = 0; u < 4; ++u) {                // all indices compile-time
            int s = ss[u];
            if (s != 0xFFFF) {
                v[u * 3 + 0] = cbase[s * 3 + 0];
                v[u * 3 + 1] = cbase[s * 3 + 1];
                v[u * 3 + 2] = cbase[s * 3 + 2];
            } else {
                v[u * 3 + 0] = 0.0f;
                v[u * 3 + 1] = 0.0f;
                v[u * 3 + 2] = 0.0f;
            }
        }
        float4* o4 = reinterpret_cast<float4*>(obase + (size_t)j0 * 3);
        o4[0] = make_float4(v[0], v[1], v[2],  v[3]);
        o4[1] = make_float4(v[4], v[5], v[6],  v[7]);
        o4[2] = make_float4(v[8], v[9], v[10], v[11]);
    }
}

extern "C" void kernel_launch(void* const* d_in, const int* in_sizes, int n_in,
                              void* d_out, int out_size, void* d_ws, size_t ws_size,
                              hipStream_t stream) {
    const float* coords = (const float*)d_in[0];
    const int*   types  = (const int*)d_in[1];
    const int*   nums   = (const int*)d_in[2];
    const int B = in_sizes[2];            // num_atoms has B elements

    float* out     = (float*)d_out;
    float* out_cnt = out + (size_t)B * 3 * NATOMS;
    float* out_off = out_cnt + (size_t)B * NTYPE;

    typed_coords_kernel<<<B, NB, 0, stream>>>(coords, types, nums,
                                              out, out_cnt, out_off);
}

// Round 4
// 40.605 us; speedup vs baseline: 1.7018x; 1.7018x over previous
//
#include <hip/hip_runtime.h>

#define NB 512          // threads per block (8 waves)
#define APT 16          // atoms per thread (N = NB*APT = 8192)
#define NTYPE 11
#define CPAD 13         // padded per-thread counter row
#define NATOMS 8192
#define HALF 4096       // dst-range tile (two passes)

__global__ __launch_bounds__(NB, 4)
void typed_coords_kernel(const float* __restrict__ coords,
                         const int*   __restrict__ types,
                         const int*   __restrict__ num_atoms,
                         float* __restrict__ out,       // B*3N floats
                         float* __restrict__ out_cnt,   // B*NTYPE floats
                         float* __restrict__ out_off)   // B*NTYPE floats
{
    const int b    = blockIdx.x;
    const int tid  = threadIdx.x;
    const int lane = tid & 63;
    const int wave = tid >> 6;

    __shared__ float lds_half[HALF * 3];             // 48 KB dst-range tile
    __shared__ unsigned short lds_cnt[NB * CPAD];    // 13.3 KB counters
    __shared__ int lds_counts[NTYPE];
    __shared__ int lds_off[NTYPE];

    const int na     = num_atoms[b];
    const int base_i = tid * APT;

    // ---- load my 16 types AND 48 coord floats into registers up front ----
    // (coord latency hides under histogram + scan)
    int   ty[APT];
    float cf[APT * 3];
    const int* tptr = types + (size_t)b * NATOMS + base_i;
    if (base_i < na) {
        #pragma unroll
        for (int g = 0; g < APT / 4; ++g) {
            int4 v = *reinterpret_cast<const int4*>(tptr + g * 4);
            ty[g * 4 + 0] = v.x;
            ty[g * 4 + 1] = v.y;
            ty[g * 4 + 2] = v.z;
            ty[g * 4 + 3] = v.w;
        }
        const float4* c4 = reinterpret_cast<const float4*>(
            coords + (size_t)b * 3 * NATOMS + (size_t)base_i * 3);  // 192B-aligned
        #pragma unroll
        for (int g = 0; g < (APT * 3) / 4; ++g) {
            *reinterpret_cast<float4*>(&cf[g * 4]) = c4[g];         // static idx
        }
    }

    // ---- per-thread histogram in own LDS row ----
    #pragma unroll
    for (int t = 0; t < CPAD; ++t) lds_cnt[tid * CPAD + t] = 0;
    if (base_i < na) {
        #pragma unroll
        for (int k = 0; k < APT; ++k) {              // static indices only
            if (base_i + k < na) lds_cnt[tid * CPAD + ty[k]] += 1;
        }
    }
    __syncthreads();

    // ---- per-type exclusive scan across the 512 thread rows ----
    // wave w handles types w, w+8
    for (int tt = wave; tt < NTYPE; tt += NB / 64) {
        int run = 0;
        #pragma unroll
        for (int s = 0; s < NB / 64; ++s) {
            int idx = (s * 64 + lane) * CPAD + tt;
            int v = lds_cnt[idx];
            int x = v;
            #pragma unroll
            for (int d = 1; d < 64; d <<= 1) {
                int n = __shfl_up(x, d);
                if (lane >= d) x += n;
            }
            lds_cnt[idx] = (unsigned short)(x - v + run);  // exclusive prefix
            run += __shfl(x, 63);
        }
        lds_counts[tt] = run;
    }
    __syncthreads();

    // ---- type offsets (exclusive cumsum over 11 types) ----
    if (tid == 0) {
        int acc = 0;
        #pragma unroll
        for (int t = 0; t < NTYPE; ++t) { lds_off[t] = acc; acc += lds_counts[t]; }
    }
    __syncthreads();

    if (tid < NTYPE) {
        out_cnt[(size_t)b * NTYPE + tid] = (float)lds_counts[tid];
        out_off[(size_t)b * NTYPE + tid] = (float)lds_off[tid];
    }

    // ---- compute each atom's destination once (registers) ----
    int dst[APT];
    #pragma unroll
    for (int k = 0; k < APT; ++k) dst[k] = 0x7FFFFFFF;
    if (base_i < na) {
        #pragma unroll
        for (int k = 0; k < APT; ++k) {
            if (base_i + k < na) {
                int t   = ty[k];
                int idx = tid * CPAD + t;
                int r   = lds_cnt[idx];
                lds_cnt[idx] = (unsigned short)(r + 1);
                dst[k] = lds_off[t] + r;
            }
        }
    }

    // ---- two dst-range passes through the 48 KB tile ----
    #pragma unroll
    for (int p = 0; p < 2; ++p) {
        if (p) __syncthreads();                      // prev writeout done

        // zero-fill invalid region [max(na,p*HALF), (p+1)*HALF) of this tile
        int lo = na - p * HALF;
        if (lo < 0) lo = 0;
        for (int i = 3 * lo + tid; i < 3 * HALF; i += NB) lds_half[i] = 0.0f;

        // scatter my atoms whose dst falls in this range
        if (base_i < na) {
            #pragma unroll
            for (int k = 0; k < APT; ++k) {
                int d = dst[k] - p * HALF;
                if (d >= 0 && d < HALF) {
                    lds_half[d * 3 + 0] = cf[k * 3 + 0];
                    lds_half[d * 3 + 1] = cf[k * 3 + 1];
                    lds_half[d * 3 + 2] = cf[k * 3 + 2];
                }
            }
        }
        __syncthreads();

        // fully-coalesced float4 writeout of this half tile
        float4* o4 = reinterpret_cast<float4*>(
            out + (size_t)b * 3 * NATOMS + (size_t)p * HALF * 3);
        const float4* l4 = reinterpret_cast<const float4*>(lds_half);
        #pragma unroll
        for (int q = 0; q < (HALF * 3 / 4) / NB; ++q) {   // 6 iterations
            o4[q * NB + tid] = l4[q * NB + tid];
        }
    }
}

extern "C" void kernel_launch(void* const* d_in, const int* in_sizes, int n_in,
                              void* d_out, int out_size, void* d_ws, size_t ws_size,
                              hipStream_t stream) {
    const float* coords = (const float*)d_in[0];
    const int*   types  = (const int*)d_in[1];
    const int*   nums   = (const int*)d_in[2];
    const int B = in_sizes[2];            // num_atoms has B elements

    float* out     = (float*)d_out;
    float* out_cnt = out + (size_t)B * 3 * NATOMS;
    float* out_off = out_cnt + (size_t)B * NTYPE;

    typed_coords_kernel<<<B, NB, 0, stream>>>(coords, types, nums,
                                              out, out_cnt, out_off);
}